// Round 12
// baseline (475.410 us; speedup 1.0000x reference)
//
#include <hip/hip_runtime.h>
#include <stdint.h>

#define COLS 4096
#define CAP  512
#define NEGV (-1000.0f)

// monotone float-bits -> uint key: a > b (as floats) <=> key(a) > key(b)
__device__ __forceinline__ uint32_t f2k(uint32_t u) {
    return u ^ (uint32_t)(((int32_t)u >> 31) | (int32_t)0x80000000);
}
// exact inverse
__device__ __forceinline__ float k2f(uint32_t k) {
    uint32_t u = (k & 0x80000000u) ? (k ^ 0x80000000u) : ~k;
    return __uint_as_float(u);
}

extern "C" __global__ __launch_bounds__(64, 4)
void intent_dropout_kernel(const float* __restrict__ x,
                           const int* __restrict__ pp,
                           float* __restrict__ out) {
    // one wave per block per row: all LDS is wave-private
    __shared__ uint64_t s_pairs[CAP];   // candidate (key,~idx) pairs
    __shared__ uint32_t s_hist[256];
    __shared__ uint64_t s_l2[64];       // in-bin finalists

    const int l   = threadIdx.x;        // lane 0..63
    const int row = blockIdx.x;
    const uint32_t P = (uint32_t)pp[0]; // == 64 (valid for P <= 64)

    const uint4* xr   = (const uint4*)(x + (size_t)row * COLS);
    float4*      orow = (float4*)(out + (size_t)row * COLS);

    // zero hist up front (visibility covered by S1)
    s_hist[l] = 0u; s_hist[l + 64] = 0u; s_hist[l + 128] = 0u; s_hist[l + 192] = 0u;

    // ---- load row -> keys in regs (static indexing only); per-lane max ----
    uint32_t k[64];
    uint32_t m = 0u;
#pragma unroll
    for (int q = 0; q < 16; ++q) {
        uint4 u = xr[l + 64 * q];
        uint32_t a = f2k(u.x), b = f2k(u.y), c = f2k(u.z), d = f2k(u.w);
        k[4*q+0] = a; k[4*q+1] = b; k[4*q+2] = c; k[4*q+3] = d;
        m = max(m, max(max(a, b), max(c, d)));
    }
    // Ck = wave-min of per-lane maxes => >= 64 elements with key >= Ck (64 groups of 64)
    uint32_t Ck = m;
#pragma unroll
    for (int d = 1; d < 64; d <<= 1) Ck = min(Ck, (uint32_t)__shfl_xor((int)Ck, d));

    // ---- per-lane candidate count + wave exclusive prefix ----
    uint32_t c = 0;
#pragma unroll
    for (int i = 0; i < 64; ++i) c += (uint32_t)(k[i] >= Ck);
    uint32_t inc = c;
#pragma unroll
    for (int d = 1; d < 64; d <<= 1) {
        uint32_t t = (uint32_t)__shfl_up((int)inc, d);
        if (l >= d) inc += t;
    }
    const uint32_t M = (uint32_t)__shfl((int)inc, 63);   // >= 64 guaranteed
    uint32_t off = inc - c;

    uint64_t cutPair;

    if (M <= CAP) {
        // ---- compact candidates into LDS as u64 (key<<32)|~idx ----
#pragma unroll
        for (int q = 0; q < 16; ++q) {
#pragma unroll
            for (int cc = 0; cc < 4; ++cc) {
                uint32_t kk = k[4*q+cc];
                if (kk >= Ck) {
                    uint32_t idx = (uint32_t)(4*l + 256*q + cc);
                    s_pairs[off++] = ((uint64_t)kk << 32) | (uint32_t)(~idx);
                }
            }
        }
        __syncthreads();   // S1 (1-wave block: lgkm drain, near-free)

        // ---- redistribute <=8 pairs/lane; candidate-key min/max ----
        uint64_t pr[8];
        bool     va[8];
#pragma unroll
        for (int q = 0; q < 8; ++q) {
            uint32_t slot = (uint32_t)l + 64u * q;
            va[q] = slot < M;
            pr[q] = va[q] ? s_pairs[slot] : 0ull;
        }
        uint32_t mnK = 0xFFFFFFFFu, mxK = 0u;
#pragma unroll
        for (int q = 0; q < 8; ++q)
            if (va[q]) { uint32_t kk = (uint32_t)(pr[q] >> 32); mnK = min(mnK, kk); mxK = max(mxK, kk); }
#pragma unroll
        for (int d = 1; d < 64; d <<= 1) {
            mnK = min(mnK, (uint32_t)__shfl_xor((int)mnK, d));
            mxK = max(mxK, (uint32_t)__shfl_xor((int)mxK, d));
        }
        uint32_t dk = mnK ^ mxK;
        int shift = 0;
        if (dk) { int hb = 31 - __clz(dk); shift = hb > 7 ? hb - 7 : 0; }
        // all candidate keys share bits above hb => (key>>shift)&255 is a monotone 256-bin map

        // ---- 256-bin hist (~1-2 entries/bin: no hot-bin serialization) ----
#pragma unroll
        for (int q = 0; q < 8; ++q)
            if (va[q]) atomicAdd(&s_hist[(((uint32_t)(pr[q] >> 32)) >> shift) & 255u], 1u);
        __syncthreads();   // S2

        // ---- suffix walk: bin containing pair-rank P (counting by key bins) ----
        uint32_t own0 = s_hist[4*l], own1 = s_hist[4*l+1], own2 = s_hist[4*l+2], own3 = s_hist[4*l+3];
        uint32_t L = own0 + own1 + own2 + own3;
        uint32_t sfx = L;
#pragma unroll
        for (int d = 1; d < 64; d <<= 1) {
            uint32_t t = (uint32_t)__shfl_down((int)sfx, d);
            if (l + d < 64) sfx += t;
        }
        uint32_t U = sfx - L;                    // count in bins above lane's range
        uint32_t tb = 0, rb = 0; bool found = false;
        {
            uint32_t hh[4] = {own0, own1, own2, own3};
            uint32_t acc = U;
#pragma unroll
            for (int i = 3; i >= 0; --i) {
                uint32_t h = hh[i];
                if (h && acc < P && P <= acc + h) { tb = (uint32_t)(4*l + i); rb = P - acc; found = true; }
                acc += h;
            }
        }
        unsigned long long fm = __ballot(found);  // exactly one lane
        int src = (int)__builtin_ctzll(fm);
        tb = (uint32_t)__shfl((int)tb, src);
        rb = (uint32_t)__shfl((int)rb, src);

        // ---- gather in-bin pairs (typically 1-4) ----
        bool ib[8];
        uint32_t c2 = 0;
#pragma unroll
        for (int q = 0; q < 8; ++q) {
            ib[q] = va[q] && ((((uint32_t)(pr[q] >> 32)) >> shift) & 255u) == tb;
            c2 += (uint32_t)ib[q];
        }
        uint32_t inc2 = c2;
#pragma unroll
        for (int d = 1; d < 64; d <<= 1) {
            uint32_t t = (uint32_t)__shfl_up((int)inc2, d);
            if (l >= d) inc2 += t;
        }
        const uint32_t n2 = (uint32_t)__shfl((int)inc2, 63);
        uint32_t o2 = inc2 - c2;

        if (n2 <= 64u) {
#pragma unroll
            for (int q = 0; q < 8; ++q)
                if (ib[q]) s_l2[o2++] = pr[q];
            __syncthreads();   // S3
            uint64_t mine = (l < (int)n2) ? s_l2[l] : 0ull;
            uint32_t r = 0;
            for (uint32_t e = 0; e < n2; ++e) r += (uint32_t)(s_l2[e] > mine);   // broadcast reads
            bool hit = (l < (int)n2) && (r == rb - 1u);   // unique: pairs distinct
            unsigned long long hm = __ballot(hit);
            int hs = (int)__builtin_ctzll(hm);
            cutPair = __shfl(mine, hs);
        } else {
            // cold: exact 64-bit MSB descent over candidate pairs, rank P
            uint64_t prefix = 0ull; uint32_t rem = P;
            for (int b = 63; b >= 0; --b) {
                uint64_t candp = (prefix >> b) | 1ull;
                uint32_t cnt = 0;
#pragma unroll
                for (int q = 0; q < 8; ++q)
                    cnt += (uint32_t)(va[q] && (pr[q] >> b) == candp);
#pragma unroll
                for (int d = 1; d < 64; d <<= 1) cnt += (uint32_t)__shfl_xor((int)cnt, d);
                if (cnt >= rem) prefix |= (1ull << b); else rem -= cnt;
            }
            cutPair = prefix;
        }
    } else {
        // very cold (M > CAP): exact descent over in-reg keys, pairs on the fly
        uint64_t prefix = 0ull; uint32_t rem = P;
        for (int b = 63; b >= 0; --b) {
            uint64_t candp = (prefix >> b) | 1ull;
            uint32_t cnt = 0;
#pragma unroll
            for (int q = 0; q < 16; ++q) {
#pragma unroll
                for (int cc = 0; cc < 4; ++cc) {
                    uint32_t idx = (uint32_t)(4*l + 256*q + cc);
                    uint64_t pv = ((uint64_t)k[4*q+cc] << 32) | (uint32_t)(~idx);
                    cnt += (uint32_t)((pv >> b) == candp);
                }
            }
#pragma unroll
            for (int d = 1; d < 64; d <<= 1) cnt += (uint32_t)__shfl_xor((int)cnt, d);
            if (cnt >= rem) prefix |= (1ull << b); else rem -= cnt;
        }
        cutPair = prefix;
    }

    // ---- masked write: kill iff (key,~idx) pair >= cutPair (exactly top-64, ties by low idx) ----
    const uint32_t Tkey = (uint32_t)(cutPair >> 32);
    const uint32_t Tlow = (uint32_t)cutPair;
#pragma unroll
    for (int q = 0; q < 16; ++q) {
        float4 o;
        float* c4 = (float*)&o;
#pragma unroll
        for (int cc = 0; cc < 4; ++cc) {
            uint32_t kk = k[4*q+cc];
            uint32_t ic = ~(uint32_t)(4*l + 256*q + cc);
            bool kill = (kk > Tkey) || (kk == Tkey && ic >= Tlow);
            c4[cc] = kill ? NEGV : k2f(kk);
        }
        orow[l + 64 * q] = o;
    }
}

extern "C" void kernel_launch(void* const* d_in, const int* in_sizes, int n_in,
                              void* d_out, int out_size, void* d_ws, size_t ws_size,
                              hipStream_t stream) {
    const float* x   = (const float*)d_in[0];
    const int*   pp  = (const int*)d_in[1];
    float*       out = (float*)d_out;
    int rows = in_sizes[0] / COLS;           // 8192
    hipLaunchKernelGGL(intent_dropout_kernel, dim3(rows), dim3(64), 0, stream,
                       x, pp, out);
}